// Round 2
// baseline (124.552 us; speedup 1.0000x reference)
//
#include <hip/hip_runtime.h>

#define NB 4
#define TT 512          // TQ = TP
#define DD 256
#define K2L2E    2.885390081777927f     // 2*log2(e): e^{2x} = 2^{K*x}
#define NEG2L2E (-2.885390081777927f)

#if defined(__has_builtin)
# if __has_builtin(__builtin_amdgcn_global_load_lds)
#  define HAS_GLL 1
# endif
#endif

typedef float v2f __attribute__((ext_vector_type(2)));

__device__ __forceinline__ v2f pk_fma(v2f a, v2f b, v2f c) {
#if defined(__has_builtin)
# if __has_builtin(__builtin_elementwise_fma)
    return __builtin_elementwise_fma(a, b, c);
# else
    v2f r; r.x = __builtin_fmaf(a.x, b.x, c.x); r.y = __builtin_fmaf(a.y, b.y, c.y); return r;
# endif
#else
    v2f r; r.x = __builtin_fmaf(a.x, b.x, c.x); r.y = __builtin_fmaf(a.y, b.y, c.y); return r;
#endif
}
__device__ __forceinline__ v2f splat2(float s) { v2f r; r.x = s; r.y = s; return r; }

__device__ __forceinline__ void stage16(const float* __restrict__ g, float* l) {
#ifdef HAS_GLL
    __builtin_amdgcn_global_load_lds((const __attribute__((address_space(1))) void*)g,
                                     (__attribute__((address_space(3))) void*)l, 16, 0, 0);
#else
    *(float4*)l = *(const float4*)g;
#endif
}

// ============ P1: projections + exp epilogue (v2: 64x64 tile, 4x4 microtile) ============
// expQ[b][d][q] = e^{2*(q@W0)[q,d]}  (TRANSPOSED, q-minor)
// expP[b][p][d] = e^{2*(p@W1)[p,d]}  (NATURAL, d-minor)
// 2048 rows (batch-folded) x 256 cols per half; grid 2*(32 mt x 4 nt) = 256 blocks,
// 256 thr, 4m x 4n per thread. K in 8 chunks of 32, DOUBLE-BUFFERED, one barrier
// per chunk. B staged async [k][64n] (linear lane order); A transpose-staged via
// registers with next-chunk prefetch, LD=68 pad (write conflicts 2-way = free).
// Per kk: 2x ds_read_b128 per 16 FMA -> VALU-bound (~1024 pk-cycles/chunk/thread).
__global__ __launch_bounds__(256) void proj_exp_kernel(
    const float* __restrict__ qin, const float* __restrict__ pin,
    const float* __restrict__ W0, const float* __restrict__ W1,
    float* __restrict__ expQ, float* __restrict__ expP)
{
    const int blk = blockIdx.x;
    const int wh = blk >> 7, tid = blk & 127;
    const int m0 = (tid >> 2) * 64, n0 = (tid & 3) * 64;
    const float* A = wh ? pin : qin;
    const float* W = wh ? W1 : W0;

    __shared__ __align__(16) float As[2][32 * 68];   // [k][m], padded
    __shared__ __align__(16) float Bs[2][32 * 64];   // [k][n]

    const int t = threadIdx.x;
    const int ar = t >> 2, ac4 = (t & 3) * 4;        // A: row m0+ar, k-cols ac4, ac4+16
    const int br = t >> 4, bc4 = (t & 15) * 4;       // B: k-rows br, br+16, cols bc4
    // microtile index roles swap per output orientation (store-coalescing)
    const int tm = wh ? (t >> 4) : (t & 15);
    const int tn = wh ? (t & 15) : (t >> 4);

    const float* Ap = A + (long)(m0 + ar) * DD + ac4;

    // regs for chunk 0
    float4 av0 = *(const float4*)(Ap);
    float4 av1 = *(const float4*)(Ap + 16);

    // prologue: stage B(0) async, write As(0), prefetch A-regs(1)
    stage16(W + (long)br * DD + n0 + bc4,        &Bs[0][t * 4]);
    stage16(W + (long)(16 + br) * DD + n0 + bc4, &Bs[0][1024 + t * 4]);
    #pragma unroll
    for (int j = 0; j < 4; ++j) {
        As[0][(ac4 + j) * 68 + ar]      = ((const float*)&av0)[j];
        As[0][(16 + ac4 + j) * 68 + ar] = ((const float*)&av1)[j];
    }
    av0 = *(const float4*)(Ap + 32);
    av1 = *(const float4*)(Ap + 48);
    __syncthreads();   // drains vmcnt -> Bs[0] ready; As[0] writes visible

    v2f acc[4][2];
    #pragma unroll
    for (int i = 0; i < 4; ++i) { acc[i][0] = splat2(0.f); acc[i][1] = splat2(0.f); }

    int buf = 0;
    for (int c = 0; c < 8; ++c) {
        if (c < 7) {
            const int k1 = (c + 1) * 32;
            stage16(W + (long)(k1 + br) * DD + n0 + bc4,      &Bs[buf ^ 1][t * 4]);
            stage16(W + (long)(k1 + 16 + br) * DD + n0 + bc4, &Bs[buf ^ 1][1024 + t * 4]);
            #pragma unroll
            for (int j = 0; j < 4; ++j) {
                As[buf ^ 1][(ac4 + j) * 68 + ar]      = ((const float*)&av0)[j];
                As[buf ^ 1][(16 + ac4 + j) * 68 + ar] = ((const float*)&av1)[j];
            }
            if (c < 6) {
                const int k2 = (c + 2) * 32;
                av0 = *(const float4*)(Ap + k2);
                av1 = *(const float4*)(Ap + k2 + 16);
            }
        }
        const float* as = &As[buf][0];
        const float* bs = &Bs[buf][0];
        #pragma unroll
        for (int kk = 0; kk < 32; ++kk) {
            float4 a = *(const float4*)&as[kk * 68 + 4 * tm];
            float4 b = *(const float4*)&bs[kk * 64 + 4 * tn];
            v2f b01; b01.x = b.x; b01.y = b.y;
            v2f b23; b23.x = b.z; b23.y = b.w;
            acc[0][0] = pk_fma(splat2(a.x), b01, acc[0][0]);
            acc[0][1] = pk_fma(splat2(a.x), b23, acc[0][1]);
            acc[1][0] = pk_fma(splat2(a.y), b01, acc[1][0]);
            acc[1][1] = pk_fma(splat2(a.y), b23, acc[1][1]);
            acc[2][0] = pk_fma(splat2(a.z), b01, acc[2][0]);
            acc[2][1] = pk_fma(splat2(a.z), b23, acc[2][1]);
            acc[3][0] = pk_fma(splat2(a.w), b01, acc[3][0]);
            acc[3][1] = pk_fma(splat2(a.w), b23, acc[3][1]);
        }
        __syncthreads();   // buf^1 staged (vmcnt drained), buf reads done
        buf ^= 1;
    }

    float ac[4][4];
    #pragma unroll
    for (int i = 0; i < 4; ++i) {
        ac[i][0] = acc[i][0].x; ac[i][1] = acc[i][0].y;
        ac[i][2] = acc[i][1].x; ac[i][3] = acc[i][1].y;
    }

    const int bi = m0 >> 9;
    const int ml = m0 & 511;
    if (wh) {
        // natural: expP row m0+4tm+i, cols n0+4tn..+3, float4 store, tn-minor lanes
        #pragma unroll
        for (int i = 0; i < 4; ++i) {
            float4 st;
            st.x = __builtin_amdgcn_exp2f(ac[i][0] * K2L2E);
            st.y = __builtin_amdgcn_exp2f(ac[i][1] * K2L2E);
            st.z = __builtin_amdgcn_exp2f(ac[i][2] * K2L2E);
            st.w = __builtin_amdgcn_exp2f(ac[i][3] * K2L2E);
            *(float4*)(expP + (long)(m0 + 4 * tm + i) * DD + n0 + 4 * tn) = st;
        }
    } else {
        // transposed: expQ[bi][n0+4tn+j][ml+4tm..+3], float4 store, tm-minor lanes
        #pragma unroll
        for (int j = 0; j < 4; ++j) {
            int d = n0 + 4 * tn + j;
            float4 st;
            st.x = __builtin_amdgcn_exp2f(ac[0][j] * K2L2E);
            st.y = __builtin_amdgcn_exp2f(ac[1][j] * K2L2E);
            st.z = __builtin_amdgcn_exp2f(ac[2][j] * K2L2E);
            st.w = __builtin_amdgcn_exp2f(ac[3][j] * K2L2E);
            *(float4*)(expQ + ((long)bi * DD + d) * TT + ml + 4 * tm) = st;
        }
    }
}

// ============ P2: scores ============
// 64p x 64q tile, 256 thr, 4p x 4q microtile, 4 x 64-d chunks DOUBLE-BUFFERED.
// Per dq-quad: 8x ds_read_b128 covering 64 elements with batched-reciprocal math:
//   f = 1+E = pk_fma(a, B, 1);  sum v_k/f_k = (n01*t23 + n23*t01) * rcp(t01*t23)
// A-quad XOR-swizzle (row>>2)&3 via pre-swizzled global_load_lds SOURCE.
__global__ __launch_bounds__(256) void score_kernel(
    const float* __restrict__ expP, const float* __restrict__ expQ,
    const float* __restrict__ vc, float* __restrict__ ebuf, float* __restrict__ lpart)
{
    const int b = blockIdx.z, pt = blockIdx.y, qt = blockIdx.x;
    const int p0 = pt * 64, q0 = qt * 64;
    const int t  = threadIdx.x;            // 0..255
    const int qx = t & 15;                 // q = q0 + 4qx + {0..3}
    const int py = t >> 4;                 // p = p0 + 4py + {0..3}
    const int sw = py & 3;                 // A-quad swizzle key = (row>>2)&3

    __shared__ __align__(16) float PA[2][64 * 64];   // [p][d-chunk], quads swizzled
    __shared__ __align__(16) float QB[2][64 * 64];   // [d][q]
    __shared__ __align__(16) float vcs[DD];

    const float* gP = expP + ((long)b * TT + p0) * DD;   // natural [p][d]
    const float* gQ = expQ + (long)b * DD * TT + q0;     // [d][q]

    // ---- stage chunk 0 (d = 0..63)
    #pragma unroll
    for (int s = 0; s < 4; ++s) {
        int f = t + 256 * s, pr = f >> 4, j = f & 15;
        stage16(gP + (long)pr * DD + 4 * (j ^ ((pr >> 2) & 3)), &PA[0][f * 4]);
    }
    #pragma unroll
    for (int s = 0; s < 4; ++s) {
        int f = t + 256 * s, d = f >> 4, o4 = (f & 15) * 4;
        stage16(gQ + (long)d * TT + o4, &QB[0][f * 4]);
    }
    vcs[t] = vc[t];
    __syncthreads();

    v2f acc[4][2];
    #pragma unroll
    for (int i = 0; i < 4; ++i) { acc[i][0] = splat2(0.f); acc[i][1] = splat2(0.f); }
    const v2f one = splat2(1.0f);

    int buf = 0;
    for (int c = 0; c < 4; ++c) {
        if (c < 3) {
            // issue next-chunk staging BEFORE consuming current (2-phase overlap)
            const float* gPc = gP + (c + 1) * 64;
            const float* gQc = gQ + (long)(c + 1) * 64 * TT;
            #pragma unroll
            for (int s = 0; s < 4; ++s) {
                int f = t + 256 * s, pr = f >> 4, j = f & 15;
                stage16(gPc + (long)pr * DD + 4 * (j ^ ((pr >> 2) & 3)), &PA[buf ^ 1][f * 4]);
            }
            #pragma unroll
            for (int s = 0; s < 4; ++s) {
                int f = t + 256 * s, d = f >> 4, o4 = (f & 15) * 4;
                stage16(gQc + (long)d * TT + o4, &QB[buf ^ 1][f * 4]);
            }
        }
        const float* vcb = &vcs[c * 64];
        const float* pa = &PA[buf][0];
        const float* qb = &QB[buf][0];
        #pragma unroll 4
        for (int dq = 0; dq < 16; ++dq) {
            float4 vq = *(const float4*)&vcb[4 * dq];
            float4 B0 = *(const float4*)&qb[(4 * dq + 0) * 64 + 4 * qx];
            float4 B1 = *(const float4*)&qb[(4 * dq + 1) * 64 + 4 * qx];
            float4 B2 = *(const float4*)&qb[(4 * dq + 2) * 64 + 4 * qx];
            float4 B3 = *(const float4*)&qb[(4 * dq + 3) * 64 + 4 * qx];
            const int sq = 4 * (dq ^ sw);
            float4 A0 = *(const float4*)&pa[(4 * py + 0) * 64 + sq];
            float4 A1 = *(const float4*)&pa[(4 * py + 1) * 64 + sq];
            float4 A2 = *(const float4*)&pa[(4 * py + 2) * 64 + sq];
            float4 A3 = *(const float4*)&pa[(4 * py + 3) * 64 + sq];
            v2f b0l; b0l.x = B0.x; b0l.y = B0.y;  v2f b0h; b0h.x = B0.z; b0h.y = B0.w;
            v2f b1l; b1l.x = B1.x; b1l.y = B1.y;  v2f b1h; b1h.x = B1.z; b1h.y = B1.w;
            v2f b2l; b2l.x = B2.x; b2l.y = B2.y;  v2f b2h; b2h.x = B2.z; b2h.y = B2.w;
            v2f b3l; b3l.x = B3.x; b3l.y = B3.y;  v2f b3h; b3h.x = B3.z; b3h.y = B3.w;
            #pragma unroll
            for (int i = 0; i < 4; ++i) {
                float4 a = (i == 0) ? A0 : (i == 1) ? A1 : (i == 2) ? A2 : A3;
                {   // q-pair 0 (q0,q1)
                    v2f f0 = pk_fma(splat2(a.x), b0l, one);
                    v2f f1 = pk_fma(splat2(a.y), b1l, one);
                    v2f f2 = pk_fma(splat2(a.z), b2l, one);
                    v2f f3 = pk_fma(splat2(a.w), b3l, one);
                    v2f t01 = f0 * f1;
                    v2f t23 = f2 * f3;
                    v2f den = t01 * t23;
                    v2f n01 = pk_fma(splat2(vq.x), f1, splat2(vq.y) * f0);
                    v2f n23 = pk_fma(splat2(vq.z), f3, splat2(vq.w) * f2);
                    v2f num = pk_fma(n01, t23, n23 * t01);
                    v2f r;
                    r.x = __builtin_amdgcn_rcpf(den.x);
                    r.y = __builtin_amdgcn_rcpf(den.y);
                    acc[i][0] = pk_fma(num, r, acc[i][0]);
                }
                {   // q-pair 1 (q2,q3)
                    v2f f0 = pk_fma(splat2(a.x), b0h, one);
                    v2f f1 = pk_fma(splat2(a.y), b1h, one);
                    v2f f2 = pk_fma(splat2(a.z), b2h, one);
                    v2f f3 = pk_fma(splat2(a.w), b3h, one);
                    v2f t01 = f0 * f1;
                    v2f t23 = f2 * f3;
                    v2f den = t01 * t23;
                    v2f n01 = pk_fma(splat2(vq.x), f1, splat2(vq.y) * f0);
                    v2f n23 = pk_fma(splat2(vq.z), f3, splat2(vq.w) * f2);
                    v2f num = pk_fma(n01, t23, n23 * t01);
                    v2f r;
                    r.x = __builtin_amdgcn_rcpf(den.x);
                    r.y = __builtin_amdgcn_rcpf(den.y);
                    acc[i][1] = pk_fma(num, r, acc[i][1]);
                }
            }
        }
        __syncthreads();   // drains vmcnt: buf^1 staged; all reads of buf done
        buf ^= 1;
    }

    // e = exp2(NEG2L2E * acc); float4 write + per-block column partial sums
    float* eb = ebuf + ((long)b * TT + p0) * TT + q0;
    float4 colp; colp.x = 0.f; colp.y = 0.f; colp.z = 0.f; colp.w = 0.f;
    #pragma unroll
    for (int i = 0; i < 4; ++i) {
        float4 ev;
        ev.x = __builtin_amdgcn_exp2f(acc[i][0].x * NEG2L2E);
        ev.y = __builtin_amdgcn_exp2f(acc[i][0].y * NEG2L2E);
        ev.z = __builtin_amdgcn_exp2f(acc[i][1].x * NEG2L2E);
        ev.w = __builtin_amdgcn_exp2f(acc[i][1].y * NEG2L2E);
        *(float4*)(eb + (long)(4 * py + i) * TT + 4 * qx) = ev;
        colp.x += ev.x; colp.y += ev.y; colp.z += ev.z; colp.w += ev.w;
    }
    float* scr = &PA[0][0];          // safe: last compute barrier already passed
    *(float4*)&scr[py * 64 + 4 * qx] = colp;
    __syncthreads();
    if (t < 64) {
        float s = 0.f;
        #pragma unroll
        for (int r = 0; r < 16; ++r) s += scr[r * 64 + t];
        lpart[((long)b * 8 + pt) * TT + q0 + t] = s;
    }
}

// ============ P3: out[b,p,:] = sum_q (e[p,q]/l[q]) * qin[b,q,:] ============
// 32p x 32d tile, 256 thr (4 waves), 4p x 4d per-lane microtile; each wave
// owns a 16-kk quarter of every 64-k chunk (k-split), LDS reduce at end.
// B staged async [k][d]; A transpose-staged with linv[k] folded in.
__global__ __launch_bounds__(256) void out_kernel(
    const float* __restrict__ ebuf, const float* __restrict__ qin,
    const float* __restrict__ lpart, float* __restrict__ out)
{
    const int b = blockIdx.z, pt = blockIdx.y, dt = blockIdx.x;
    const int m0 = pt * 32, n0 = dt * 32;
    const int t    = threadIdx.x;       // 0..255
    const int wv   = t >> 6;            // wave 0..3 -> kk quarter
    const int lane = t & 63;
    const int pg   = lane >> 3;         // p = 4*pg + i
    const int dg   = lane & 7;          // d = 4*dg + j

    __shared__ __align__(16) float smem[4 * 32 * 36];   // 18.4 KB: staging / reduce scratch
    __shared__ float linv[TT];
    float* As = smem;                    // [64k][36] transposed, linv-scaled
    float* Bs = smem + 64 * 36;          // [64k][32d]

    #pragma unroll
    for (int s = 0; s < 2; ++s) {
        int qq = t + 256 * s;
        float sum = 0.f;
        #pragma unroll
        for (int pb = 0; pb < 8; ++pb) sum += lpart[((long)b * 8 + pb) * TT + qq];
        linv[qq] = __builtin_amdgcn_rcpf(sum);
    }
    __syncthreads();

    const float* Ab = ebuf + ((long)b * TT + m0) * TT;   // 32 p-rows x 512 k
    const float* Bb = qin + (long)b * TT * DD + n0;      // 512 k-rows x 32 d

    const int ar = t >> 3, ak4 = (t & 7) * 4;            // A: p-row ar, k-quads ak4, ak4+32

    v2f acc[4][2];
    #pragma unroll
    for (int i = 0; i < 4; ++i) { acc[i][0] = splat2(0.f); acc[i][1] = splat2(0.f); }

    for (int c = 0; c < 8; ++c) {
        const int k0 = c * 64;
        // stage B async: 2048 f = 2 f4/thread, layout [k][32d]
        #pragma unroll
        for (int s = 0; s < 2; ++s) {
            int f = t + 256 * s, kr = f >> 3, d4 = (f & 7) * 4;
            stage16(Bb + (long)(k0 + kr) * DD + d4, &Bs[f * 4]);
        }
        // stage A manual: read [p][k4], scale by linv, transpose-write [k][p]
        #pragma unroll
        for (int s = 0; s < 2; ++s) {
            int kq = ak4 + 32 * s;
            float4 a = *(const float4*)(Ab + (long)ar * TT + k0 + kq);
            float4 lv = *(const float4*)&linv[k0 + kq];
            As[(kq + 0) * 36 + ar] = a.x * lv.x;
            As[(kq + 1) * 36 + ar] = a.y * lv.y;
            As[(kq + 2) * 36 + ar] = a.z * lv.z;
            As[(kq + 3) * 36 + ar] = a.w * lv.w;
        }
        __syncthreads();
        // wave wv computes kk quarter [16*wv, 16*wv+16)
        const int kb = 16 * wv;
        #pragma unroll
        for (int u = 0; u < 16; ++u) {
            int kk = kb + u;
            float4 a  = *(const float4*)&As[kk * 36 + 4 * pg];
            float4 bq = *(const float4*)&Bs[kk * 32 + 4 * dg];
            v2f b0; b0.x = bq.x; b0.y = bq.y;
            v2f b1; b1.x = bq.z; b1.y = bq.w;
            acc[0][0] = pk_fma(splat2(a.x), b0, acc[0][0]);
            acc[0][1] = pk_fma(splat2(a.x), b1, acc[0][1]);
            acc[1][0] = pk_fma(splat2(a.y), b0, acc[1][0]);
            acc[1][1] = pk_fma(splat2(a.y), b1, acc[1][1]);
            acc[2][0] = pk_fma(splat2(a.z), b0, acc[2][0]);
            acc[2][1] = pk_fma(splat2(a.z), b1, acc[2][1]);
            acc[3][0] = pk_fma(splat2(a.w), b0, acc[3][0]);
            acc[3][1] = pk_fma(splat2(a.w), b1, acc[3][1]);
        }
        __syncthreads();
    }

    // cross-wave k reduction: scratch [w][32p][36]
    float* scr = smem;
    #pragma unroll
    for (int i = 0; i < 4; ++i) {
        *(v2f*)&scr[wv * 1152 + (4 * pg + i) * 36 + 4 * dg]     = acc[i][0];
        *(v2f*)&scr[wv * 1152 + (4 * pg + i) * 36 + 4 * dg + 2] = acc[i][1];
    }
    __syncthreads();
    {
        int pr = t >> 3, d0 = (t & 7) * 4;
        float4 s0 = *(const float4*)&scr[0 * 1152 + pr * 36 + d0];
        float4 s1 = *(const float4*)&scr[1 * 1152 + pr * 36 + d0];
        float4 s2 = *(const float4*)&scr[2 * 1152 + pr * 36 + d0];
        float4 s3 = *(const float4*)&scr[3 * 1152 + pr * 36 + d0];
        float4 v;
        v.x = (s0.x + s1.x) + (s2.x + s3.x);
        v.y = (s0.y + s1.y) + (s2.y + s3.y);
        v.z = (s0.z + s1.z) + (s2.z + s3.z);
        v.w = (s0.w + s1.w) + (s2.w + s3.w);
        *(float4*)(out + ((long)b * TT + m0 + pr) * DD + n0 + d0) = v;
    }
}

extern "C" void kernel_launch(void* const* d_in, const int* in_sizes, int n_in,
                              void* d_out, int out_size, void* d_ws, size_t ws_size,
                              hipStream_t stream) {
    const float* q  = (const float*)d_in[0];
    const float* p  = (const float*)d_in[1];
    const float* W0 = (const float*)d_in[2];
    const float* W1 = (const float*)d_in[3];
    const float* vc = (const float*)d_in[4];
    float* out = (float*)d_out;

    float* ws    = (float*)d_ws;
    float* expQ  = ws;                // [4][256][512]  e^{2*projQ}, [b][d][q]
    float* expP  = ws + 524288;       // [4][512][256]  e^{2*projP}, [b][p][d]
    float* ebuf  = ws + 1048576;      // [4][512][512]
    float* lpart = ws + 2097152;      // [4][8][512]

    proj_exp_kernel<<<dim3(256), 256, 0, stream>>>(q, p, W0, W1, expQ, expP);
    score_kernel<<<dim3(8, 8, NB), 256, 0, stream>>>(expP, expQ, vc, ebuf, lpart);
    out_kernel<<<dim3(8, 16, NB), 256, 0, stream>>>(ebuf, q, lpart, out);
}

// Round 3
// 117.190 us; speedup vs baseline: 1.0628x; 1.0628x over previous
//
#include <hip/hip_runtime.h>

#define NB 4
#define TT 512          // TQ = TP
#define DD 256
#define K2L2E    2.885390081777927f     // 2*log2(e): e^{2x} = 2^{K*x}
#define NEG2L2E (-2.885390081777927f)

#if defined(__has_builtin)
# if __has_builtin(__builtin_amdgcn_global_load_lds)
#  define HAS_GLL 1
# endif
#endif

typedef float v2f __attribute__((ext_vector_type(2)));

__device__ __forceinline__ v2f pk_fma(v2f a, v2f b, v2f c) {
#if defined(__has_builtin)
# if __has_builtin(__builtin_elementwise_fma)
    return __builtin_elementwise_fma(a, b, c);
# else
    v2f r; r.x = __builtin_fmaf(a.x, b.x, c.x); r.y = __builtin_fmaf(a.y, b.y, c.y); return r;
# endif
#else
    v2f r; r.x = __builtin_fmaf(a.x, b.x, c.x); r.y = __builtin_fmaf(a.y, b.y, c.y); return r;
#endif
}
__device__ __forceinline__ v2f splat2(float s) { v2f r; r.x = s; r.y = s; return r; }

__device__ __forceinline__ void stage16(const float* __restrict__ g, float* l) {
#ifdef HAS_GLL
    __builtin_amdgcn_global_load_lds((const __attribute__((address_space(1))) void*)g,
                                     (__attribute__((address_space(3))) void*)l, 16, 0, 0);
#else
    *(float4*)l = *(const float4*)g;
#endif
}

// ============ P1: projections + exp epilogue (round-0 version — best measured) ============
// expQ[b][d][q] = e^{2*(q@W0)[q,d]}  (TRANSPOSED, q-minor)
// expP[b][p][d] = e^{2*(p@W1)[p,d]}  (NATURAL, d-minor)
__global__ __launch_bounds__(256) void proj_exp_kernel(
    const float* __restrict__ qin, const float* __restrict__ pin,
    const float* __restrict__ W0, const float* __restrict__ W1,
    float* __restrict__ expQ, float* __restrict__ expP)
{
    const int blk = blockIdx.x;
    const int wh = blk >> 8, tid = blk & 255;
    const int m0 = (tid >> 2) * 32, n0 = (tid & 3) * 64;
    const float* A = wh ? pin : qin;
    const float* W = wh ? W1 : W0;

    __shared__ __align__(16) float As[32 * 34];   // [k][m]
    __shared__ __align__(16) float Bs[32 * 64];   // [k][n]

    const int t  = threadIdx.x;
    const int ar = t >> 3, ac4 = (t & 7) * 4;
    const int br = t >> 4, bc4 = (t & 15) * 4;
    // microtile index roles swap per output orientation (store-coalescing)
    const int tm = wh ? (t >> 4) : (t & 15);
    const int tn = wh ? (t & 15) : (t >> 4);

    const float* Ap = A + (long)(m0 + ar) * DD + ac4;

    float4 av  = *(const float4*)Ap;
    float4 bv0 = *(const float4*)(W + (long)br * DD + n0 + bc4);
    float4 bv1 = *(const float4*)(W + (long)(br + 16) * DD + n0 + bc4);

    v2f accv[2][2];
    accv[0][0] = splat2(0.f); accv[0][1] = splat2(0.f);
    accv[1][0] = splat2(0.f); accv[1][1] = splat2(0.f);

    for (int c = 0; c < 8; ++c) {
        As[(ac4 + 0) * 34 + ar] = av.x;
        As[(ac4 + 1) * 34 + ar] = av.y;
        As[(ac4 + 2) * 34 + ar] = av.z;
        As[(ac4 + 3) * 34 + ar] = av.w;
        *(float4*)&Bs[br * 64 + bc4]        = bv0;
        *(float4*)&Bs[(br + 16) * 64 + bc4] = bv1;
        __syncthreads();
        if (c < 7) {
            int k1 = (c + 1) * 32;
            av  = *(const float4*)(Ap + k1);
            bv0 = *(const float4*)(W + (long)(k1 + br) * DD + n0 + bc4);
            bv1 = *(const float4*)(W + (long)(k1 + 16 + br) * DD + n0 + bc4);
        }
        #pragma unroll
        for (int kk = 0; kk < 32; ++kk) {
            float2 a = *(const float2*)&As[kk * 34 + 2 * tm];
            float4 b = *(const float4*)&Bs[kk * 64 + 4 * tn];
            v2f b01; b01.x = b.x; b01.y = b.y;
            v2f b23; b23.x = b.z; b23.y = b.w;
            accv[0][0] = pk_fma(splat2(a.x), b01, accv[0][0]);
            accv[0][1] = pk_fma(splat2(a.x), b23, accv[0][1]);
            accv[1][0] = pk_fma(splat2(a.y), b01, accv[1][0]);
            accv[1][1] = pk_fma(splat2(a.y), b23, accv[1][1]);
        }
        __syncthreads();
    }

    float acc[2][4];
    #pragma unroll
    for (int i = 0; i < 2; ++i) {
        acc[i][0] = accv[i][0].x; acc[i][1] = accv[i][0].y;
        acc[i][2] = accv[i][1].x; acc[i][3] = accv[i][1].y;
    }

    const int bi = m0 >> 9;
    const int ml = m0 & 511;
    if (wh) {
        // natural: expP[bi][ml+2tm+i][n0+4tn .. +3], float4 store, tn-minor lanes
        #pragma unroll
        for (int i = 0; i < 2; ++i) {
            float4 st;
            st.x = __builtin_amdgcn_exp2f(acc[i][0] * K2L2E);
            st.y = __builtin_amdgcn_exp2f(acc[i][1] * K2L2E);
            st.z = __builtin_amdgcn_exp2f(acc[i][2] * K2L2E);
            st.w = __builtin_amdgcn_exp2f(acc[i][3] * K2L2E);
            *(float4*)(expP + ((long)bi * TT + ml + 2 * tm + i) * DD + n0 + 4 * tn) = st;
        }
    } else {
        // transposed: expQ[bi][n0+4tn+j][ml+2tm .. +1], float2 store, tm-minor lanes
        #pragma unroll
        for (int j = 0; j < 4; ++j) {
            int d = n0 + 4 * tn + j;
            float2 st;
            st.x = __builtin_amdgcn_exp2f(acc[0][j] * K2L2E);
            st.y = __builtin_amdgcn_exp2f(acc[1][j] * K2L2E);
            *(float2*)(expQ + ((long)bi * DD + d) * TT + ml + 2 * tm) = st;
        }
    }
}

// ============ P2: scores (v3: d-split 4x4 microtile, full-tile LDS) ============
// 64p x 64q tile, 512 thr. Half-block h = t>>8 computes d in [128h, 128h+128)
// for the SAME (p,q) microtiles (4p x 4q per thread) -> 131K threads chip-wide
// (2 waves/SIMD) at 0.125 LDS-instr/element (8x ds_read_b128 per 64 elements).
// Full [64p][256d] PA + [256d][64q] QB staged ONCE (132 KB LDS, 1 block/CU),
// one barrier, barrier-free compute, then partial-acc LDS exchange + exp2.
// A-side 4-row reads conflict-free via d-quad XOR swizzle key (row>>2)&7,
// applied on the global_load_lds SOURCE (linear LDS dest) + same XOR on read.
__global__ __launch_bounds__(512) void score_kernel(
    const float* __restrict__ expP, const float* __restrict__ expQ,
    const float* __restrict__ vc, float* __restrict__ ebuf, float* __restrict__ lpart)
{
    const int b = blockIdx.z, pt = blockIdx.y, qt = blockIdx.x;
    const int p0 = pt * 64, q0 = qt * 64;
    const int t  = threadIdx.x;            // 0..511
    const int h  = t >> 8;                 // d-half: 0 -> d 0..127, 1 -> d 128..255
    const int u  = t & 255;
    const int qx = u & 15;                 // q = q0 + 4qx + {0..3}
    const int py = u >> 4;                 // p = p0 + 4py + {0..3}
    const int sw = py & 7;                 // A swizzle key = ((4py+i)>>2)&7 = py&7

    __shared__ __align__(16) float PA[64 * 256];   // [p][d], quad-swizzled; 64 KB
    __shared__ __align__(16) float QB[256 * 64];   // [d][q]; 64 KB
    __shared__ __align__(16) float vcs[DD];

    const float* gP = expP + ((long)b * TT + p0) * DD;   // natural [p][d]
    const float* gQ = expQ + (long)b * DD * TT + q0;     // [d][q]

    // ---- stage everything (async), linear LDS dest, pre-swizzled PA source
    #pragma unroll
    for (int s = 0; s < 8; ++s) {
        int f = t + 512 * s;               // 0..4095
        int pr = f >> 6, j = f & 63;       // row, d-quad
        stage16(gP + (long)pr * DD + 4 * (j ^ ((pr >> 2) & 7)), &PA[f * 4]);
    }
    #pragma unroll
    for (int s = 0; s < 8; ++s) {
        int f = t + 512 * s;
        int d = f >> 4, o4 = (f & 15) * 4;
        stage16(gQ + (long)d * TT + o4, &QB[f * 4]);
    }
    if (t < DD) vcs[t] = vc[t];
    __syncthreads();   // drains vmcnt -> all LDS ready

    v2f acc[4][2];
    #pragma unroll
    for (int i = 0; i < 4; ++i) { acc[i][0] = splat2(0.f); acc[i][1] = splat2(0.f); }
    const v2f one = splat2(1.0f);
    const float* vcb = &vcs[h * 128];

    #pragma unroll 4
    for (int dq = 0; dq < 32; ++dq) {
        const int dj = h * 32 + dq;        // global d-quad index 0..63
        float4 vq = *(const float4*)&vcb[4 * dq];
        const int sq = 4 * (dj ^ sw);
        float4 A0 = *(const float4*)&PA[(4 * py + 0) * 256 + sq];
        float4 A1 = *(const float4*)&PA[(4 * py + 1) * 256 + sq];
        float4 A2 = *(const float4*)&PA[(4 * py + 2) * 256 + sq];
        float4 A3 = *(const float4*)&PA[(4 * py + 3) * 256 + sq];
        const int db = (4 * dj) * 64 + 4 * qx;
        float4 B0 = *(const float4*)&QB[db];
        float4 B1 = *(const float4*)&QB[db + 64];
        float4 B2 = *(const float4*)&QB[db + 128];
        float4 B3 = *(const float4*)&QB[db + 192];
        v2f b0l; b0l.x = B0.x; b0l.y = B0.y;  v2f b0h; b0h.x = B0.z; b0h.y = B0.w;
        v2f b1l; b1l.x = B1.x; b1l.y = B1.y;  v2f b1h; b1h.x = B1.z; b1h.y = B1.w;
        v2f b2l; b2l.x = B2.x; b2l.y = B2.y;  v2f b2h; b2h.x = B2.z; b2h.y = B2.w;
        v2f b3l; b3l.x = B3.x; b3l.y = B3.y;  v2f b3h; b3h.x = B3.z; b3h.y = B3.w;
        #pragma unroll
        for (int i = 0; i < 4; ++i) {
            float4 a = (i == 0) ? A0 : (i == 1) ? A1 : (i == 2) ? A2 : A3;
            {   // q-pair 0 (q0,q1)
                v2f f0 = pk_fma(splat2(a.x), b0l, one);
                v2f f1 = pk_fma(splat2(a.y), b1l, one);
                v2f f2 = pk_fma(splat2(a.z), b2l, one);
                v2f f3 = pk_fma(splat2(a.w), b3l, one);
                v2f t01 = f0 * f1;
                v2f t23 = f2 * f3;
                v2f den = t01 * t23;
                v2f n01 = pk_fma(splat2(vq.x), f1, splat2(vq.y) * f0);
                v2f n23 = pk_fma(splat2(vq.z), f3, splat2(vq.w) * f2);
                v2f num = pk_fma(n01, t23, n23 * t01);
                v2f r;
                r.x = __builtin_amdgcn_rcpf(den.x);
                r.y = __builtin_amdgcn_rcpf(den.y);
                acc[i][0] = pk_fma(num, r, acc[i][0]);
            }
            {   // q-pair 1 (q2,q3)
                v2f f0 = pk_fma(splat2(a.x), b0h, one);
                v2f f1 = pk_fma(splat2(a.y), b1h, one);
                v2f f2 = pk_fma(splat2(a.z), b2h, one);
                v2f f3 = pk_fma(splat2(a.w), b3h, one);
                v2f t01 = f0 * f1;
                v2f t23 = f2 * f3;
                v2f den = t01 * t23;
                v2f n01 = pk_fma(splat2(vq.x), f1, splat2(vq.y) * f0);
                v2f n23 = pk_fma(splat2(vq.z), f3, splat2(vq.w) * f2);
                v2f num = pk_fma(n01, t23, n23 * t01);
                v2f r;
                r.x = __builtin_amdgcn_rcpf(den.x);
                r.y = __builtin_amdgcn_rcpf(den.y);
                acc[i][1] = pk_fma(num, r, acc[i][1]);
            }
        }
    }

    __syncthreads();                 // all PA/QB reads done; safe to reuse
    // ---- combine halves: h=1 publishes partial acc, h=0 adds + finishes
    float* scr = &PA[0];             // [64p][64q] exchange (16 KB)
    if (h == 1) {
        #pragma unroll
        for (int i = 0; i < 4; ++i) {
            float4 st;
            st.x = acc[i][0].x; st.y = acc[i][0].y;
            st.z = acc[i][1].x; st.w = acc[i][1].y;
            *(float4*)&scr[(4 * py + i) * 64 + 4 * qx] = st;
        }
    }
    __syncthreads();
    float* scr2 = &QB[0];            // [16][64] column partials
    if (h == 0) {
        float* eb = ebuf + ((long)b * TT + p0) * TT + q0;
        float4 colp; colp.x = 0.f; colp.y = 0.f; colp.z = 0.f; colp.w = 0.f;
        #pragma unroll
        for (int i = 0; i < 4; ++i) {
            float4 o = *(const float4*)&scr[(4 * py + i) * 64 + 4 * qx];
            float4 ev;
            ev.x = __builtin_amdgcn_exp2f((acc[i][0].x + o.x) * NEG2L2E);
            ev.y = __builtin_amdgcn_exp2f((acc[i][0].y + o.y) * NEG2L2E);
            ev.z = __builtin_amdgcn_exp2f((acc[i][1].x + o.z) * NEG2L2E);
            ev.w = __builtin_amdgcn_exp2f((acc[i][1].y + o.w) * NEG2L2E);
            *(float4*)(eb + (long)(4 * py + i) * TT + 4 * qx) = ev;
            colp.x += ev.x; colp.y += ev.y; colp.z += ev.z; colp.w += ev.w;
        }
        *(float4*)&scr2[py * 64 + 4 * qx] = colp;
    }
    __syncthreads();
    if (t < 64) {
        float s = 0.f;
        #pragma unroll
        for (int r = 0; r < 16; ++r) s += scr2[r * 64 + t];
        lpart[((long)b * 8 + pt) * TT + q0 + t] = s;
    }
}

// ============ P3: out[b,p,:] = sum_q (e[p,q]/l[q]) * qin[b,q,:] ============
// 32p x 32d tile, 256 thr (4 waves), 4p x 4d per-lane microtile; each wave
// owns a 16-kk quarter of every 64-k chunk (k-split), LDS reduce at end.
// B staged async [k][d]; A transpose-staged with linv[k] folded in.
__global__ __launch_bounds__(256) void out_kernel(
    const float* __restrict__ ebuf, const float* __restrict__ qin,
    const float* __restrict__ lpart, float* __restrict__ out)
{
    const int b = blockIdx.z, pt = blockIdx.y, dt = blockIdx.x;
    const int m0 = pt * 32, n0 = dt * 32;
    const int t    = threadIdx.x;       // 0..255
    const int wv   = t >> 6;            // wave 0..3 -> kk quarter
    const int lane = t & 63;
    const int pg   = lane >> 3;         // p = 4*pg + i
    const int dg   = lane & 7;          // d = 4*dg + j

    __shared__ __align__(16) float smem[4 * 32 * 36];   // 18.4 KB: staging / reduce scratch
    __shared__ float linv[TT];
    float* As = smem;                    // [64k][36] transposed, linv-scaled
    float* Bs = smem + 64 * 36;          // [64k][32d]

    #pragma unroll
    for (int s = 0; s < 2; ++s) {
        int qq = t + 256 * s;
        float sum = 0.f;
        #pragma unroll
        for (int pb = 0; pb < 8; ++pb) sum += lpart[((long)b * 8 + pb) * TT + qq];
        linv[qq] = __builtin_amdgcn_rcpf(sum);
    }
    __syncthreads();

    const float* Ab = ebuf + ((long)b * TT + m0) * TT;   // 32 p-rows x 512 k
    const float* Bb = qin + (long)b * TT * DD + n0;      // 512 k-rows x 32 d

    const int ar = t >> 3, ak4 = (t & 7) * 4;            // A: p-row ar, k-quads ak4, ak4+32

    v2f acc[4][2];
    #pragma unroll
    for (int i = 0; i < 4; ++i) { acc[i][0] = splat2(0.f); acc[i][1] = splat2(0.f); }

    for (int c = 0; c < 8; ++c) {
        const int k0 = c * 64;
        // stage B async: 2048 f = 2 f4/thread, layout [k][32d]
        #pragma unroll
        for (int s = 0; s < 2; ++s) {
            int f = t + 256 * s, kr = f >> 3, d4 = (f & 7) * 4;
            stage16(Bb + (long)(k0 + kr) * DD + d4, &Bs[f * 4]);
        }
        // stage A manual: read [p][k4], scale by linv, transpose-write [k][p]
        #pragma unroll
        for (int s = 0; s < 2; ++s) {
            int kq = ak4 + 32 * s;
            float4 a = *(const float4*)(Ab + (long)ar * TT + k0 + kq);
            float4 lv = *(const float4*)&linv[k0 + kq];
            As[(kq + 0) * 36 + ar] = a.x * lv.x;
            As[(kq + 1) * 36 + ar] = a.y * lv.y;
            As[(kq + 2) * 36 + ar] = a.z * lv.z;
            As[(kq + 3) * 36 + ar] = a.w * lv.w;
        }
        __syncthreads();
        // wave wv computes kk quarter [16*wv, 16*wv+16)
        const int kb = 16 * wv;
        #pragma unroll
        for (int u = 0; u < 16; ++u) {
            int kk = kb + u;
            float4 a  = *(const float4*)&As[kk * 36 + 4 * pg];
            float4 bq = *(const float4*)&Bs[kk * 32 + 4 * dg];
            v2f b0; b0.x = bq.x; b0.y = bq.y;
            v2f b1; b1.x = bq.z; b1.y = bq.w;
            acc[0][0] = pk_fma(splat2(a.x), b0, acc[0][0]);
            acc[0][1] = pk_fma(splat2(a.x), b1, acc[0][1]);
            acc[1][0] = pk_fma(splat2(a.y), b0, acc[1][0]);
            acc[1][1] = pk_fma(splat2(a.y), b1, acc[1][1]);
            acc[2][0] = pk_fma(splat2(a.z), b0, acc[2][0]);
            acc[2][1] = pk_fma(splat2(a.z), b1, acc[2][1]);
            acc[3][0] = pk_fma(splat2(a.w), b0, acc[3][0]);
            acc[3][1] = pk_fma(splat2(a.w), b1, acc[3][1]);
        }
        __syncthreads();
    }

    // cross-wave k reduction: scratch [w][32p][36]
    float* scr = smem;
    #pragma unroll
    for (int i = 0; i < 4; ++i) {
        *(v2f*)&scr[wv * 1152 + (4 * pg + i) * 36 + 4 * dg]     = acc[i][0];
        *(v2f*)&scr[wv * 1152 + (4 * pg + i) * 36 + 4 * dg + 2] = acc[i][1];
    }
    __syncthreads();
    {
        int pr = t >> 3, d0 = (t & 7) * 4;
        float4 s0 = *(const float4*)&scr[0 * 1152 + pr * 36 + d0];
        float4 s1 = *(const float4*)&scr[1 * 1152 + pr * 36 + d0];
        float4 s2 = *(const float4*)&scr[2 * 1152 + pr * 36 + d0];
        float4 s3 = *(const float4*)&scr[3 * 1152 + pr * 36 + d0];
        float4 v;
        v.x = (s0.x + s1.x) + (s2.x + s3.x);
        v.y = (s0.y + s1.y) + (s2.y + s3.y);
        v.z = (s0.z + s1.z) + (s2.z + s3.z);
        v.w = (s0.w + s1.w) + (s2.w + s3.w);
        *(float4*)(out + ((long)b * TT + m0 + pr) * DD + n0 + d0) = v;
    }
}

extern "C" void kernel_launch(void* const* d_in, const int* in_sizes, int n_in,
                              void* d_out, int out_size, void* d_ws, size_t ws_size,
                              hipStream_t stream) {
    const float* q  = (const float*)d_in[0];
    const float* p  = (const float*)d_in[1];
    const float* W0 = (const float*)d_in[2];
    const float* W1 = (const float*)d_in[3];
    const float* vc = (const float*)d_in[4];
    float* out = (float*)d_out;

    float* ws    = (float*)d_ws;
    float* expQ  = ws;                // [4][256][512]  e^{2*projQ}, [b][d][q]
    float* expP  = ws + 524288;       // [4][512][256]  e^{2*projP}, [b][p][d]
    float* ebuf  = ws + 1048576;      // [4][512][512]
    float* lpart = ws + 2097152;      // [4][8][512]

    proj_exp_kernel<<<dim3(512), 256, 0, stream>>>(q, p, W0, W1, expQ, expP);
    score_kernel<<<dim3(8, 8, NB), 512, 0, stream>>>(expP, expQ, vc, ebuf, lpart);
    out_kernel<<<dim3(8, 16, NB), 256, 0, stream>>>(ebuf, q, lpart, out);
}

// Round 4
// 116.518 us; speedup vs baseline: 1.0690x; 1.0058x over previous
//
#include <hip/hip_runtime.h>

#define NB 4
#define TT 512          // TQ = TP
#define DD 256
#define K2L2E    2.885390081777927f     // 2*log2(e): e^{2x} = 2^{K*x}
#define NEG2L2E (-2.885390081777927f)

#if defined(__has_builtin)
# if __has_builtin(__builtin_amdgcn_global_load_lds)
#  define HAS_GLL 1
# endif
#endif

typedef float v2f __attribute__((ext_vector_type(2)));

__device__ __forceinline__ v2f pk_fma(v2f a, v2f b, v2f c) {
#if defined(__has_builtin)
# if __has_builtin(__builtin_elementwise_fma)
    return __builtin_elementwise_fma(a, b, c);
# else
    v2f r; r.x = __builtin_fmaf(a.x, b.x, c.x); r.y = __builtin_fmaf(a.y, b.y, c.y); return r;
# endif
#else
    v2f r; r.x = __builtin_fmaf(a.x, b.x, c.x); r.y = __builtin_fmaf(a.y, b.y, c.y); return r;
#endif
}
__device__ __forceinline__ v2f splat2(float s) { v2f r; r.x = s; r.y = s; return r; }

__device__ __forceinline__ void stage16(const float* __restrict__ g, float* l) {
#ifdef HAS_GLL
    __builtin_amdgcn_global_load_lds((const __attribute__((address_space(1))) void*)g,
                                     (__attribute__((address_space(3))) void*)l, 16, 0, 0);
#else
    *(float4*)l = *(const float4*)g;
#endif
}

// ============ P1: projections + exp epilogue (round-0 version — best measured) ============
// expQ[b][d][q] = e^{2*(q@W0)[q,d]}  (TRANSPOSED, q-minor)
// expP[b][p][d] = e^{2*(p@W1)[p,d]}  (NATURAL, d-minor)
__global__ __launch_bounds__(256) void proj_exp_kernel(
    const float* __restrict__ qin, const float* __restrict__ pin,
    const float* __restrict__ W0, const float* __restrict__ W1,
    float* __restrict__ expQ, float* __restrict__ expP)
{
    const int blk = blockIdx.x;
    const int wh = blk >> 8, tid = blk & 255;
    const int m0 = (tid >> 2) * 32, n0 = (tid & 3) * 64;
    const float* A = wh ? pin : qin;
    const float* W = wh ? W1 : W0;

    __shared__ __align__(16) float As[32 * 34];   // [k][m]
    __shared__ __align__(16) float Bs[32 * 64];   // [k][n]

    const int t  = threadIdx.x;
    const int ar = t >> 3, ac4 = (t & 7) * 4;
    const int br = t >> 4, bc4 = (t & 15) * 4;
    // microtile index roles swap per output orientation (store-coalescing)
    const int tm = wh ? (t >> 4) : (t & 15);
    const int tn = wh ? (t & 15) : (t >> 4);

    const float* Ap = A + (long)(m0 + ar) * DD + ac4;

    float4 av  = *(const float4*)Ap;
    float4 bv0 = *(const float4*)(W + (long)br * DD + n0 + bc4);
    float4 bv1 = *(const float4*)(W + (long)(br + 16) * DD + n0 + bc4);

    v2f accv[2][2];
    accv[0][0] = splat2(0.f); accv[0][1] = splat2(0.f);
    accv[1][0] = splat2(0.f); accv[1][1] = splat2(0.f);

    for (int c = 0; c < 8; ++c) {
        As[(ac4 + 0) * 34 + ar] = av.x;
        As[(ac4 + 1) * 34 + ar] = av.y;
        As[(ac4 + 2) * 34 + ar] = av.z;
        As[(ac4 + 3) * 34 + ar] = av.w;
        *(float4*)&Bs[br * 64 + bc4]        = bv0;
        *(float4*)&Bs[(br + 16) * 64 + bc4] = bv1;
        __syncthreads();
        if (c < 7) {
            int k1 = (c + 1) * 32;
            av  = *(const float4*)(Ap + k1);
            bv0 = *(const float4*)(W + (long)(k1 + br) * DD + n0 + bc4);
            bv1 = *(const float4*)(W + (long)(k1 + 16 + br) * DD + n0 + bc4);
        }
        #pragma unroll
        for (int kk = 0; kk < 32; ++kk) {
            float2 a = *(const float2*)&As[kk * 34 + 2 * tm];
            float4 b = *(const float4*)&Bs[kk * 64 + 4 * tn];
            v2f b01; b01.x = b.x; b01.y = b.y;
            v2f b23; b23.x = b.z; b23.y = b.w;
            accv[0][0] = pk_fma(splat2(a.x), b01, accv[0][0]);
            accv[0][1] = pk_fma(splat2(a.x), b23, accv[0][1]);
            accv[1][0] = pk_fma(splat2(a.y), b01, accv[1][0]);
            accv[1][1] = pk_fma(splat2(a.y), b23, accv[1][1]);
        }
        __syncthreads();
    }

    float acc[2][4];
    #pragma unroll
    for (int i = 0; i < 2; ++i) {
        acc[i][0] = accv[i][0].x; acc[i][1] = accv[i][0].y;
        acc[i][2] = accv[i][1].x; acc[i][3] = accv[i][1].y;
    }

    const int bi = m0 >> 9;
    const int ml = m0 & 511;
    if (wh) {
        // natural: expP[bi][ml+2tm+i][n0+4tn .. +3], float4 store, tn-minor lanes
        #pragma unroll
        for (int i = 0; i < 2; ++i) {
            float4 st;
            st.x = __builtin_amdgcn_exp2f(acc[i][0] * K2L2E);
            st.y = __builtin_amdgcn_exp2f(acc[i][1] * K2L2E);
            st.z = __builtin_amdgcn_exp2f(acc[i][2] * K2L2E);
            st.w = __builtin_amdgcn_exp2f(acc[i][3] * K2L2E);
            *(float4*)(expP + ((long)bi * TT + ml + 2 * tm + i) * DD + n0 + 4 * tn) = st;
        }
    } else {
        // transposed: expQ[bi][n0+4tn+j][ml+2tm .. +1], float2 store, tm-minor lanes
        #pragma unroll
        for (int j = 0; j < 4; ++j) {
            int d = n0 + 4 * tn + j;
            float2 st;
            st.x = __builtin_amdgcn_exp2f(acc[0][j] * K2L2E);
            st.y = __builtin_amdgcn_exp2f(acc[1][j] * K2L2E);
            *(float2*)(expQ + ((long)bi * DD + d) * TT + ml + 2 * tm) = st;
        }
    }
}

// ============ P2: scores (v3: d-split 4x4 microtile, full-tile LDS) ============
// 64p x 64q tile, 512 thr. Half-block h = t>>8 computes d in [128h, 128h+128)
// for the SAME (p,q) microtiles (4p x 4q per thread) -> 131K threads chip-wide
// (2 waves/SIMD) at 0.125 LDS-instr/element (8x ds_read_b128 per 64 elements).
// Full [64p][256d] PA + [256d][64q] QB staged ONCE (132 KB LDS, 1 block/CU),
// one barrier, barrier-free compute, then partial-acc LDS exchange + exp2.
// A-side 4-row reads conflict-free via d-quad XOR swizzle key (row>>2)&7,
// applied on the global_load_lds SOURCE (linear LDS dest) + same XOR on read.
__global__ __launch_bounds__(512) void score_kernel(
    const float* __restrict__ expP, const float* __restrict__ expQ,
    const float* __restrict__ vc, float* __restrict__ ebuf, float* __restrict__ lpart)
{
    const int b = blockIdx.z, pt = blockIdx.y, qt = blockIdx.x;
    const int p0 = pt * 64, q0 = qt * 64;
    const int t  = threadIdx.x;            // 0..511
    const int h  = t >> 8;                 // d-half: 0 -> d 0..127, 1 -> d 128..255
    const int u  = t & 255;
    const int qx = u & 15;                 // q = q0 + 4qx + {0..3}
    const int py = u >> 4;                 // p = p0 + 4py + {0..3}
    const int sw = py & 7;                 // A swizzle key = ((4py+i)>>2)&7 = py&7

    __shared__ __align__(16) float PA[64 * 256];   // [p][d], quad-swizzled; 64 KB
    __shared__ __align__(16) float QB[256 * 64];   // [d][q]; 64 KB
    __shared__ __align__(16) float vcs[DD];

    const float* gP = expP + ((long)b * TT + p0) * DD;   // natural [p][d]
    const float* gQ = expQ + (long)b * DD * TT + q0;     // [d][q]

    // ---- stage everything (async), linear LDS dest, pre-swizzled PA source
    #pragma unroll
    for (int s = 0; s < 8; ++s) {
        int f = t + 512 * s;               // 0..4095
        int pr = f >> 6, j = f & 63;       // row, d-quad
        stage16(gP + (long)pr * DD + 4 * (j ^ ((pr >> 2) & 7)), &PA[f * 4]);
    }
    #pragma unroll
    for (int s = 0; s < 8; ++s) {
        int f = t + 512 * s;
        int d = f >> 4, o4 = (f & 15) * 4;
        stage16(gQ + (long)d * TT + o4, &QB[f * 4]);
    }
    if (t < DD) vcs[t] = vc[t];
    __syncthreads();   // drains vmcnt -> all LDS ready

    v2f acc[4][2];
    #pragma unroll
    for (int i = 0; i < 4; ++i) { acc[i][0] = splat2(0.f); acc[i][1] = splat2(0.f); }
    const v2f one = splat2(1.0f);
    const float* vcb = &vcs[h * 128];

    #pragma unroll 4
    for (int dq = 0; dq < 32; ++dq) {
        const int dj = h * 32 + dq;        // global d-quad index 0..63
        float4 vq = *(const float4*)&vcb[4 * dq];
        const int sq = 4 * (dj ^ sw);
        float4 A0 = *(const float4*)&PA[(4 * py + 0) * 256 + sq];
        float4 A1 = *(const float4*)&PA[(4 * py + 1) * 256 + sq];
        float4 A2 = *(const float4*)&PA[(4 * py + 2) * 256 + sq];
        float4 A3 = *(const float4*)&PA[(4 * py + 3) * 256 + sq];
        const int db = (4 * dj) * 64 + 4 * qx;
        float4 B0 = *(const float4*)&QB[db];
        float4 B1 = *(const float4*)&QB[db + 64];
        float4 B2 = *(const float4*)&QB[db + 128];
        float4 B3 = *(const float4*)&QB[db + 192];
        v2f b0l; b0l.x = B0.x; b0l.y = B0.y;  v2f b0h; b0h.x = B0.z; b0h.y = B0.w;
        v2f b1l; b1l.x = B1.x; b1l.y = B1.y;  v2f b1h; b1h.x = B1.z; b1h.y = B1.w;
        v2f b2l; b2l.x = B2.x; b2l.y = B2.y;  v2f b2h; b2h.x = B2.z; b2h.y = B2.w;
        v2f b3l; b3l.x = B3.x; b3l.y = B3.y;  v2f b3h; b3h.x = B3.z; b3h.y = B3.w;
        #pragma unroll
        for (int i = 0; i < 4; ++i) {
            float4 a = (i == 0) ? A0 : (i == 1) ? A1 : (i == 2) ? A2 : A3;
            {   // q-pair 0 (q0,q1)
                v2f f0 = pk_fma(splat2(a.x), b0l, one);
                v2f f1 = pk_fma(splat2(a.y), b1l, one);
                v2f f2 = pk_fma(splat2(a.z), b2l, one);
                v2f f3 = pk_fma(splat2(a.w), b3l, one);
                v2f t01 = f0 * f1;
                v2f t23 = f2 * f3;
                v2f den = t01 * t23;
                v2f n01 = pk_fma(splat2(vq.x), f1, splat2(vq.y) * f0);
                v2f n23 = pk_fma(splat2(vq.z), f3, splat2(vq.w) * f2);
                v2f num = pk_fma(n01, t23, n23 * t01);
                v2f r;
                r.x = __builtin_amdgcn_rcpf(den.x);
                r.y = __builtin_amdgcn_rcpf(den.y);
                acc[i][0] = pk_fma(num, r, acc[i][0]);
            }
            {   // q-pair 1 (q2,q3)
                v2f f0 = pk_fma(splat2(a.x), b0h, one);
                v2f f1 = pk_fma(splat2(a.y), b1h, one);
                v2f f2 = pk_fma(splat2(a.z), b2h, one);
                v2f f3 = pk_fma(splat2(a.w), b3h, one);
                v2f t01 = f0 * f1;
                v2f t23 = f2 * f3;
                v2f den = t01 * t23;
                v2f n01 = pk_fma(splat2(vq.x), f1, splat2(vq.y) * f0);
                v2f n23 = pk_fma(splat2(vq.z), f3, splat2(vq.w) * f2);
                v2f num = pk_fma(n01, t23, n23 * t01);
                v2f r;
                r.x = __builtin_amdgcn_rcpf(den.x);
                r.y = __builtin_amdgcn_rcpf(den.y);
                acc[i][1] = pk_fma(num, r, acc[i][1]);
            }
        }
    }

    __syncthreads();                 // all PA/QB reads done; safe to reuse
    // ---- combine halves: h=1 publishes partial acc, h=0 adds + finishes
    float* scr = &PA[0];             // [64p][64q] exchange (16 KB)
    if (h == 1) {
        #pragma unroll
        for (int i = 0; i < 4; ++i) {
            float4 st;
            st.x = acc[i][0].x; st.y = acc[i][0].y;
            st.z = acc[i][1].x; st.w = acc[i][1].y;
            *(float4*)&scr[(4 * py + i) * 64 + 4 * qx] = st;
        }
    }
    __syncthreads();
    float* scr2 = &QB[0];            // [16][64] column partials
    if (h == 0) {
        float* eb = ebuf + ((long)b * TT + p0) * TT + q0;
        float4 colp; colp.x = 0.f; colp.y = 0.f; colp.z = 0.f; colp.w = 0.f;
        #pragma unroll
        for (int i = 0; i < 4; ++i) {
            float4 o = *(const float4*)&scr[(4 * py + i) * 64 + 4 * qx];
            float4 ev;
            ev.x = __builtin_amdgcn_exp2f((acc[i][0].x + o.x) * NEG2L2E);
            ev.y = __builtin_amdgcn_exp2f((acc[i][0].y + o.y) * NEG2L2E);
            ev.z = __builtin_amdgcn_exp2f((acc[i][1].x + o.z) * NEG2L2E);
            ev.w = __builtin_amdgcn_exp2f((acc[i][1].y + o.w) * NEG2L2E);
            *(float4*)(eb + (long)(4 * py + i) * TT + 4 * qx) = ev;
            colp.x += ev.x; colp.y += ev.y; colp.z += ev.z; colp.w += ev.w;
        }
        *(float4*)&scr2[py * 64 + 4 * qx] = colp;
    }
    __syncthreads();
    if (t < 64) {
        float s = 0.f;
        #pragma unroll
        for (int r = 0; r < 16; ++r) s += scr2[r * 64 + t];
        lpart[((long)b * 8 + pt) * TT + q0 + t] = s;
    }
}

// ============ P3: out[b,p,:] = sum_q (e[p,q]/l[q]) * qin[b,q,:] ============
// v2: DOUBLE-BUFFERED. 32p x 32d tile, 256 thr (4 waves), 4p x 4d microtile;
// each wave owns a 16-kk quarter of every 64-k chunk (k-split), LDS reduce at
// end. B staged async [k][d] into buf^1 while computing buf; A global loads
// register-prefetched TWO chunks ahead (P1-r0 pattern), transpose-written with
// linv[k] folded in. ONE barrier per chunk (was two). LDS 36.9 KB -> 2 blk/CU.
__global__ __launch_bounds__(256) void out_kernel(
    const float* __restrict__ ebuf, const float* __restrict__ qin,
    const float* __restrict__ lpart, float* __restrict__ out)
{
    const int b = blockIdx.z, pt = blockIdx.y, dt = blockIdx.x;
    const int m0 = pt * 32, n0 = dt * 32;
    const int t    = threadIdx.x;       // 0..255
    const int wv   = t >> 6;            // wave 0..3 -> kk quarter
    const int lane = t & 63;
    const int pg   = lane >> 3;         // p = 4*pg + i
    const int dg   = lane & 7;          // d = 4*dg + j

    __shared__ __align__(16) float As[2][64 * 36];   // 18.4 KB (also reduce scratch)
    __shared__ __align__(16) float Bs[2][64 * 32];   // 16.4 KB
    __shared__ float linv[TT];                       // 2 KB

    #pragma unroll
    for (int s = 0; s < 2; ++s) {
        int qq = t + 256 * s;
        float sum = 0.f;
        #pragma unroll
        for (int pb = 0; pb < 8; ++pb) sum += lpart[((long)b * 8 + pb) * TT + qq];
        linv[qq] = __builtin_amdgcn_rcpf(sum);
    }
    __syncthreads();   // linv ready (needed for As writes below)

    const float* Ab = ebuf + ((long)b * TT + m0) * TT;   // 32 p-rows x 512 k
    const float* Bb = qin + (long)b * TT * DD + n0;      // 512 k-rows x 32 d

    const int ar = t >> 3, ak4 = (t & 7) * 4;            // A: p-row ar, k-quads ak4, ak4+32
    const float* Arow = Ab + (long)ar * TT;
    const int bkr = t >> 3, bd4 = (t & 7) * 4;           // B: k-row bkr (+32), col-quad bd4

    // ---- prologue: stage chunk 0, prefetch A-regs for chunk 1
    stage16(Bb + (long)bkr * DD + bd4,        &Bs[0][t * 4]);
    stage16(Bb + (long)(bkr + 32) * DD + bd4, &Bs[0][1024 + t * 4]);
    float4 av0 = *(const float4*)(Arow + ak4);
    float4 av1 = *(const float4*)(Arow + ak4 + 32);
    {
        float4 l0 = *(const float4*)&linv[ak4];
        float4 l1 = *(const float4*)&linv[ak4 + 32];
        As[0][(ak4 + 0) * 36 + ar] = av0.x * l0.x;
        As[0][(ak4 + 1) * 36 + ar] = av0.y * l0.y;
        As[0][(ak4 + 2) * 36 + ar] = av0.z * l0.z;
        As[0][(ak4 + 3) * 36 + ar] = av0.w * l0.w;
        As[0][(ak4 + 32) * 36 + ar] = av1.x * l1.x;
        As[0][(ak4 + 33) * 36 + ar] = av1.y * l1.y;
        As[0][(ak4 + 34) * 36 + ar] = av1.z * l1.z;
        As[0][(ak4 + 35) * 36 + ar] = av1.w * l1.w;
    }
    av0 = *(const float4*)(Arow + 64 + ak4);
    av1 = *(const float4*)(Arow + 64 + ak4 + 32);
    __syncthreads();   // drains vmcnt: Bs[0] ready, As[0] visible

    v2f acc[4][2];
    #pragma unroll
    for (int i = 0; i < 4; ++i) { acc[i][0] = splat2(0.f); acc[i][1] = splat2(0.f); }

    int buf = 0;
    for (int c = 0; c < 8; ++c) {
        if (c < 7) {
            const int k1 = (c + 1) * 64;
            // stage B(c+1) async into buf^1
            stage16(Bb + (long)(k1 + bkr) * DD + bd4,      &Bs[buf ^ 1][t * 4]);
            stage16(Bb + (long)(k1 + 32 + bkr) * DD + bd4, &Bs[buf ^ 1][1024 + t * 4]);
            // write As(c+1) from prefetched regs, linv folded
            float4 l0 = *(const float4*)&linv[k1 + ak4];
            float4 l1 = *(const float4*)&linv[k1 + ak4 + 32];
            As[buf ^ 1][(ak4 + 0) * 36 + ar] = av0.x * l0.x;
            As[buf ^ 1][(ak4 + 1) * 36 + ar] = av0.y * l0.y;
            As[buf ^ 1][(ak4 + 2) * 36 + ar] = av0.z * l0.z;
            As[buf ^ 1][(ak4 + 3) * 36 + ar] = av0.w * l0.w;
            As[buf ^ 1][(ak4 + 32) * 36 + ar] = av1.x * l1.x;
            As[buf ^ 1][(ak4 + 33) * 36 + ar] = av1.y * l1.y;
            As[buf ^ 1][(ak4 + 34) * 36 + ar] = av1.z * l1.z;
            As[buf ^ 1][(ak4 + 35) * 36 + ar] = av1.w * l1.w;
            if (c < 6) {
                const int k2 = (c + 2) * 64;
                av0 = *(const float4*)(Arow + k2 + ak4);
                av1 = *(const float4*)(Arow + k2 + ak4 + 32);
            }
        }
        const float* as = &As[buf][0];
        const float* bs = &Bs[buf][0];
        const int kb = 16 * wv;
        #pragma unroll
        for (int u = 0; u < 16; ++u) {
            int kk = kb + u;
            float4 a  = *(const float4*)&as[kk * 36 + 4 * pg];
            float4 bq = *(const float4*)&bs[kk * 32 + 4 * dg];
            v2f b0; b0.x = bq.x; b0.y = bq.y;
            v2f b1; b1.x = bq.z; b1.y = bq.w;
            acc[0][0] = pk_fma(splat2(a.x), b0, acc[0][0]);
            acc[0][1] = pk_fma(splat2(a.x), b1, acc[0][1]);
            acc[1][0] = pk_fma(splat2(a.y), b0, acc[1][0]);
            acc[1][1] = pk_fma(splat2(a.y), b1, acc[1][1]);
            acc[2][0] = pk_fma(splat2(a.z), b0, acc[2][0]);
            acc[2][1] = pk_fma(splat2(a.z), b1, acc[2][1]);
            acc[3][0] = pk_fma(splat2(a.w), b0, acc[3][0]);
            acc[3][1] = pk_fma(splat2(a.w), b1, acc[3][1]);
        }
        __syncthreads();   // buf^1 staged (vmcnt drained), buf reads done
        buf ^= 1;
    }

    // cross-wave k reduction: scratch [w][32p][36] (reuses As[0..1], 4608 f)
    float* scr = &As[0][0];
    #pragma unroll
    for (int i = 0; i < 4; ++i) {
        *(v2f*)&scr[wv * 1152 + (4 * pg + i) * 36 + 4 * dg]     = acc[i][0];
        *(v2f*)&scr[wv * 1152 + (4 * pg + i) * 36 + 4 * dg + 2] = acc[i][1];
    }
    __syncthreads();
    {
        int pr = t >> 3, d0 = (t & 7) * 4;
        float4 s0 = *(const float4*)&scr[0 * 1152 + pr * 36 + d0];
        float4 s1 = *(const float4*)&scr[1 * 1152 + pr * 36 + d0];
        float4 s2 = *(const float4*)&scr[2 * 1152 + pr * 36 + d0];
        float4 s3 = *(const float4*)&scr[3 * 1152 + pr * 36 + d0];
        float4 v;
        v.x = (s0.x + s1.x) + (s2.x + s3.x);
        v.y = (s0.y + s1.y) + (s2.y + s3.y);
        v.z = (s0.z + s1.z) + (s2.z + s3.z);
        v.w = (s0.w + s1.w) + (s2.w + s3.w);
        *(float4*)(out + ((long)b * TT + m0 + pr) * DD + n0 + d0) = v;
    }
}

extern "C" void kernel_launch(void* const* d_in, const int* in_sizes, int n_in,
                              void* d_out, int out_size, void* d_ws, size_t ws_size,
                              hipStream_t stream) {
    const float* q  = (const float*)d_in[0];
    const float* p  = (const float*)d_in[1];
    const float* W0 = (const float*)d_in[2];
    const float* W1 = (const float*)d_in[3];
    const float* vc = (const float*)d_in[4];
    float* out = (float*)d_out;

    float* ws    = (float*)d_ws;
    float* expQ  = ws;                // [4][256][512]  e^{2*projQ}, [b][d][q]
    float* expP  = ws + 524288;       // [4][512][256]  e^{2*projP}, [b][p][d]
    float* ebuf  = ws + 1048576;      // [4][512][512]
    float* lpart = ws + 2097152;      // [4][8][512]

    proj_exp_kernel<<<dim3(512), 256, 0, stream>>>(q, p, W0, W1, expQ, expP);
    score_kernel<<<dim3(8, 8, NB), 512, 0, stream>>>(expP, expQ, vc, ebuf, lpart);
    out_kernel<<<dim3(8, 16, NB), 256, 0, stream>>>(ebuf, q, lpart, out);
}